// Round 1
// baseline (2595.202 us; speedup 1.0000x reference)
//
#include <hip/hip_runtime.h>

#define BATCH   8
#define NPTS    8192
#define NPOINT  1024
#define NSAMPLE 32
#define CHANC   32
#define OUTC    35          // 3 xyz + 32 point channels
#define R2      0.0625f     // 0.25^2

#define NSUBB   8                   // sub-blocks (CUs) per batch
#define WPB     4                   // waves per block
#define NSLOT   (NSUBB * WPB)       // 32 wave-slots per batch

typedef float v2f __attribute__((ext_vector_type(2)));
typedef unsigned long long u64;
typedef unsigned int u32;

// DPP helpers --------------------------------------------------------------
template <int CTRL>
__device__ __forceinline__ float dpp_max_step(float v) {
    int r = __builtin_amdgcn_update_dpp(__float_as_int(v), __float_as_int(v),
                                        CTRL, 0xf, 0xf, false);
    return fmaxf(v, __int_as_float(r));
}
// u64 max across lanes: DPP the two halves, integer compare (no FP edge cases)
template <int CTRL>
__device__ __forceinline__ u64 dpp_umax64_step(u64 k) {
    int lo = __builtin_amdgcn_update_dpp((int)(u32)k, (int)(u32)k,
                                         CTRL, 0xf, 0xf, false);
    int hi = __builtin_amdgcn_update_dpp((int)(u32)(k >> 32), (int)(u32)(k >> 32),
                                         CTRL, 0xf, 0xf, false);
    u64 r = ((u64)(u32)hi << 32) | (u64)(u32)lo;
    return r > k ? r : k;
}
#define DPP_ROW_SHR(n)  (0x110 | (n))
#define DPP_BCAST15     0x142
#define DPP_BCAST31     0x143

// ---------------------------------------------------------------------------
// Kernel 1: furthest point sampling — MULTI-CU version. 8 blocks x 256
// threads per batch (64 blocks total, 1 block/CU due to 128 KB LDS mirror,
// all co-resident). Each wave owns 256 points (4/thread, registers).
// Per-iteration cross-wave argmax exchange via a global mailbox of 32
// tagged u64 wave-slots per batch (tag<<45 | val_bits<<13 | ~idx), agent-
// scope relaxed atomics (LLC-coherent across XCDs), parity double-buffered
// (writer can't lap readers: s+2 write requires everyone published s+1,
// which requires everyone consumed s). NO barriers in the 1023-iter loop.
// Arithmetic / fmin order / lowest-index tie-break bit-identical to the
// single-CU version (absmax 0.0). Slots memset to 0 per launch (stale-tag
// kill across graph replays).
// ---------------------------------------------------------------------------
__global__ __launch_bounds__(256) void fps_kernel(const float* __restrict__ xyz,
                                                  float* __restrict__ new_xyz,
                                                  float4* __restrict__ xyz4,
                                                  u64* __restrict__ slots) {
#pragma clang fp contract(off)
    const int blk  = blockIdx.x;
    const int b    = blk & 7;            // batch (same-XCD affinity for a batch)
    const int sub  = blk >> 3;           // sub-block 0..7
    const int t    = threadIdx.x;        // 0..255
    const int lane = t & 63;
    const int wloc = t >> 6;             // 0..3
    const int wid  = sub * WPB + wloc;   // wave id within batch, 0..31
    const float* bx = xyz + (size_t)b * NPTS * 3;
    u64* bslots = slots + (size_t)b * (2 * NSLOT);   // [parity][NSLOT]

    __shared__ float4 pts[NPTS];         // 128 KB mirror, XOR-swizzled

    // ---- mirror fill: thread t loads 32 contiguous pts (96 floats) ----
    {
        float f[96];
        float4* fq = (float4*)f;
        const float4* s4 = (const float4*)bx + (size_t)t * 24;
#pragma unroll
        for (int q = 0; q < 24; ++q) fq[q] = s4[q];
#pragma unroll
        for (int i = 0; i < 32; ++i) {
            const int j  = t * 32 + i;
            const int js = j ^ ((j >> 4) & 7);      // bank swizzle
            pts[js] = make_float4(f[3 * i + 0], f[3 * i + 1], f[3 * i + 2], 0.0f);
        }
    }

    // ---- own 4 update-points from global (48B contiguous, aligned) ----
    v2f px[2], py[2], pz[2], dist[2];
    const int p0 = wid * 256 + (lane << 2);          // global point index base
    {
        float f[12];
        float4* fq = (float4*)f;
        const float4* s4 = (const float4*)(bx + (size_t)p0 * 3);
#pragma unroll
        for (int q = 0; q < 3; ++q) fq[q] = s4[q];
#pragma unroll
        for (int p = 0; p < 2; ++p) {
            px[p] = (v2f){f[6 * p + 0], f[6 * p + 3]};
            py[p] = (v2f){f[6 * p + 1], f[6 * p + 4]};
            pz[p] = (v2f){f[6 * p + 2], f[6 * p + 5]};
            dist[p] = (v2f){1e38f, 1e38f};
        }
    }
    __syncthreads();   // only barrier in the kernel (mirror ready)

    // ---- early dump of packed xyz4 for ballgroup (sub 0 only) ----
    if (sub == 0) {
        float4* wb = xyz4 + (size_t)b * NPTS;
#pragma unroll
        for (int q = 0; q < 32; ++q) {
            const int p  = q * 256 + t;
            const int ps = p ^ ((p >> 4) & 7);      // un-swizzle
            wb[p] = pts[ps];
        }
    }

    // seed: xyz[b, 0]  (swizzle(0) == 0)
    float4 c0 = pts[0];
    float lx = c0.x, ly = c0.y, lz = c0.z;
    if (sub == 0 && t == 0) {
        float* o = new_xyz + (size_t)b * NPOINT * 3;
        o[0] = lx; o[1] = ly; o[2] = lz;
    }

    for (int s = 1; s < NPOINT; ++s) {
        // --- packed update + serial inline argmax over 4 points ---
        const v2f lx2 = (v2f){lx, lx};
        const v2f ly2 = (v2f){ly, ly};
        const v2f lz2 = (v2f){lz, lz};
        float bestv = -1.0f;
        int   bi    = 0;
#pragma unroll
        for (int p = 0; p < 2; ++p) {
            const v2f dx = px[p] - lx2;
            const v2f dy = py[p] - ly2;
            const v2f dz = pz[p] - lz2;
            const v2f d2 = (dx * dx + dy * dy) + dz * dz;   // contract off -> exact
            const float d0 = fminf(dist[p].x, d2.x);
            const float d1 = fminf(dist[p].y, d2.y);
            dist[p] = (v2f){d0, d1};
            if (d0 > bestv) { bestv = d0; bi = 2 * p; }     // strict > keeps lowest i
            if (d1 > bestv) { bestv = d1; bi = 2 * p + 1; }
        }
        const int besti = p0 + bi;

        // --- wave64 max via DPP ---
        float v = bestv;
        v = dpp_max_step<DPP_ROW_SHR(1)>(v);
        v = dpp_max_step<DPP_ROW_SHR(2)>(v);
        v = dpp_max_step<DPP_ROW_SHR(4)>(v);
        v = dpp_max_step<DPP_ROW_SHR(8)>(v);
        v = dpp_max_step<DPP_BCAST15>(v);
        v = dpp_max_step<DPP_BCAST31>(v);
        const float smax = __int_as_float(__builtin_amdgcn_readlane(__float_as_int(v), 63));

        // leader lane (lowest lane holding max == lowest index) publishes record
        const u64 m   = __ballot(bestv == smax);
        const int par = s & 1;
        if (lane == (int)__builtin_ctzll(m)) {
            const u64 rec = ((u64)(u32)s << 45)
                          | ((u64)__float_as_uint(smax) << 13)
                          | (u64)((~besti) & 0x1FFF);
            __hip_atomic_store(&bslots[par * NSLOT + wid], rec,
                               __ATOMIC_RELAXED, __HIP_MEMORY_SCOPE_AGENT);
        }
        asm volatile("" ::: "memory");   // compiler fence: store stays above poll

        // --- poll all 32 wave-slots (lanes 0..31), tag == s means ready ---
        u64 key = 0;
        if (lane < 32) {
            u64* ps = &bslots[par * NSLOT + lane];
            u64 rv;
            do {
                rv = __hip_atomic_load(ps, __ATOMIC_RELAXED, __HIP_MEMORY_SCOPE_AGENT);
            } while (__ballot((int)(rv >> 45) == s) != 0x00000000FFFFFFFFull);
            key = rv & ((1ull << 45) - 1);           // val<<13 | ~idx13
        }

        // --- wave-wide u64 max over the 32 keys (lanes>=32 hold 0) ---
        key = dpp_umax64_step<DPP_ROW_SHR(1)>(key);
        key = dpp_umax64_step<DPP_ROW_SHR(2)>(key);
        key = dpp_umax64_step<DPP_ROW_SHR(4)>(key);
        key = dpp_umax64_step<DPP_ROW_SHR(8)>(key);
        key = dpp_umax64_step<DPP_BCAST15>(key);
        key = dpp_umax64_step<DPP_BCAST31>(key);
        const u32 klo = (u32)__builtin_amdgcn_readlane((int)(u32)key, 63);
        const int idx = (int)((~klo) & 0x1FFF);

        const int js  = idx ^ ((idx >> 4) & 7);
        const float4 cw = pts[js];               // uniform -> broadcast b128
        lx = cw.x; ly = cw.y; lz = cw.z;
        if (sub == 0 && t == 0) {
            float* o = new_xyz + ((size_t)b * NPOINT + s) * 3;
            o[0] = lx; o[1] = ly; o[2] = lz;
        }
    }
}

// ---------------------------------------------------------------------------
// Kernel 2: ball query + grouping — UNCHANGED (best measured shape).
// One block (4 waves) per center; wave r scans quarter r in 8 superrounds
// of 256 pts with coalesced float4 loads from the packed xyz4 workspace.
// Quarter results prefix-merged (exact first-32-ascending + first-hit pad).
// Gather: 256 threads over 32x35, coalesced stores.
// ---------------------------------------------------------------------------
__global__ __launch_bounds__(256) void ballgroup_kernel(const float4* __restrict__ xyz4,
                                                        const float* __restrict__ points,
                                                        const float* __restrict__ new_xyz,
                                                        float* __restrict__ out) {
#pragma clang fp contract(off)
    const int tid  = threadIdx.x;
    const int lane = tid & 63;
    const int r    = tid >> 6;            // wave id = quarter id, 0..3
    const int gw   = blockIdx.x;          // center id, 0..8191
    const int b    = gw >> 10;

    const float4* bx4 = xyz4 + (size_t)b * NPTS;
    const float*  cen = new_xyz + (size_t)gw * 3;
    const float cx = cen[0], cy = cen[1], cz = cen[2];

    __shared__ int qidx[4][NSAMPLE];
    __shared__ int qcnt[4];

    // --- scan this wave's quarter: 2048 pts, 8 superrounds of 256 ---
    int k = 0;
    const int qbase = r << 11;
    for (int base = qbase; base < qbase + 2048; base += 256) {
        // phase 1: hoist 4 coalesced dwordx4 loads (independent)
        float4 p4[4];
#pragma unroll
        for (int u = 0; u < 4; ++u) p4[u] = bx4[base + u * 64 + lane];
        // phase 2: distances + masks (no memory)
        bool in[4];
#pragma unroll
        for (int u = 0; u < 4; ++u) {
            const float dx = p4[u].x - cx;
            const float dy = p4[u].y - cy;
            const float dz = p4[u].z - cz;
            const float d2 = (dx * dx + dy * dy) + dz * dz;   // contract off
            in[u] = d2 < R2;
        }
        // phase 3: serial bookkeeping (no loads on chain)
#pragma unroll
        for (int u = 0; u < 4; ++u) {
            const unsigned long long mu = __ballot(in[u]);
            const int pre = __popcll(mu & ((1ull << lane) - 1ull));
            if (in[u] && (k + pre) < NSAMPLE) qidx[r][k + pre] = base + u * 64 + lane;
            k += __popcll(mu);
        }
        if (k >= NSAMPLE) break;          // one exit check per superround
    }
    if (k > NSAMPLE) k = NSAMPLE;
    if (lane == 0) qcnt[r] = k;
    __syncthreads();

    // --- prefix-merge: first NSAMPLE of the concatenated quarters ---
    const int c0n = qcnt[0], c1n = qcnt[1], c2n = qcnt[2], c3n = qcnt[3];
    const int o1 = c0n, o2 = c0n + c1n, o3 = o2 + c2n;
    const int total = o3 + c3n;
    const int kk = total < NSAMPLE ? total : NSAMPLE;
    // first hit overall = first entry of the first nonempty quarter
    // (center's own point has d2==0, so total >= 1 always)
    const int r0 = (c0n > 0) ? 0 : (c1n > 0) ? 1 : (c2n > 0) ? 2 : 3;
    const int firstIdx = qidx[r0][0];

    // --- gather: 32x35 output elems across 256 threads, coalesced ---
    float*       o    = out + (size_t)gw * NSAMPLE * OUTC;
    const float* prow = points + (size_t)b * NPTS * CHANC;
    for (int e = tid; e < NSAMPLE * OUTC; e += 256) {
        const int s = e / OUTC;
        const int c = e - s * OUTC;
        int j;
        if (s < kk) {
            const int rr  = (int)(s >= o1) + (int)(s >= o2) + (int)(s >= o3);
            const int off = (rr == 0) ? 0 : (rr == 1) ? o1 : (rr == 2) ? o2 : o3;
            j = qidx[rr][s - off];
        } else {
            j = firstIdx;
        }
        float v;
        if (c < 3) {
            const float4 pj = bx4[j];
            const float pv = (c == 0) ? pj.x : (c == 1) ? pj.y : pj.z;
            const float cc = (c == 0) ? cx : (c == 1) ? cy : cz;
            v = pv - cc;
        } else {
            v = prow[j * CHANC + (c - 3)];
        }
        o[e] = v;   // consecutive lanes -> consecutive addresses (coalesced)
    }
}

// ---------------------------------------------------------------------------
extern "C" void kernel_launch(void* const* d_in, const int* in_sizes, int n_in,
                              void* d_out, int out_size, void* d_ws, size_t ws_size,
                              hipStream_t stream) {
    const float* xyz    = (const float*)d_in[0];   // (8, 8192, 3)  fp32
    const float* points = (const float*)d_in[1];   // (8, 8192, 32) fp32
    float* new_xyz    = (float*)d_out;                         // (8,1024,3)
    float* new_points = new_xyz + (size_t)BATCH * NPOINT * 3;  // (8,1024,32,35)
    float4* xyz4      = (float4*)d_ws;                         // 512 KB packed
    u64*    slots     = (u64*)((char*)d_ws + (size_t)BATCH * NPTS * sizeof(float4));

    // kill stale tags from previous graph replay (4 KB)
    hipMemsetAsync(slots, 0, (size_t)BATCH * 2 * NSLOT * sizeof(u64), stream);

    fps_kernel<<<BATCH * NSUBB, 256, 0, stream>>>(xyz, new_xyz, xyz4, slots);
    ballgroup_kernel<<<BATCH * NPOINT, 256, 0, stream>>>(xyz4, points, new_xyz, new_points);
}

// Round 2
// 1076.376 us; speedup vs baseline: 2.4111x; 2.4111x over previous
//
#include <hip/hip_runtime.h>

#define BATCH   8
#define NPTS    8192
#define NPOINT  1024
#define NSAMPLE 32
#define CHANC   32
#define OUTC    35          // 3 xyz + 32 point channels
#define R2      0.0625f     // 0.25^2

typedef float v2f __attribute__((ext_vector_type(2)));

// DPP helpers --------------------------------------------------------------
template <int CTRL>
__device__ __forceinline__ float dpp_max_step(float v) {
    int r = __builtin_amdgcn_update_dpp(__float_as_int(v), __float_as_int(v),
                                        CTRL, 0xf, 0xf, false);
    return fmaxf(v, __int_as_float(r));
}
#define DPP_ROW_SHR(n)  (0x110 | (n))
#define DPP_BCAST15     0x142
#define DPP_BCAST31     0x143

__device__ __forceinline__ unsigned long long u64max(unsigned long long a,
                                                     unsigned long long b) {
    return a > b ? a : b;
}

// Packed f32 VOP3P helpers (hand-forced: hipcc scalarizes v2f float math,
// especially with fp contract off — R2 theory: that scalarization is the
// dominant VALU-issue cost). Per-component IEEE results identical to the
// scalar sequence: sub, mul, add in the same association order.
__device__ __forceinline__ v2f pk_sub(v2f a, v2f b) {
    v2f d;
    asm("v_pk_add_f32 %0, %1, %2 neg_lo:[0,1] neg_hi:[0,1]"
        : "=v"(d) : "v"(a), "v"(b));
    return d;
}
__device__ __forceinline__ v2f pk_mul(v2f a, v2f b) {
    v2f d;
    asm("v_pk_mul_f32 %0, %1, %2" : "=v"(d) : "v"(a), "v"(b));
    return d;
}
__device__ __forceinline__ v2f pk_add(v2f a, v2f b) {
    v2f d;
    asm("v_pk_add_f32 %0, %1, %2" : "=v"(d) : "v"(a), "v"(b));
    return d;
}

// ---------------------------------------------------------------------------
// Kernel 1: furthest point sampling — FROZEN round-9 structure (898 µs,
// single block per batch) with the distance core hand-packed via VOP3P
// inline asm. One block per batch, 512 threads, 16 contiguous pts/thread.
// Bit-exact fp32 (contract off semantics preserved: separate pk_mul +
// pk_add, same association), serial inline argmax, DPP wave max + ballot
// leader, packed u64 (val<<32|~idx) partial, one barrier/iter (parity
// dbuf), depth-3 u64 tree scan, coords via XOR-swizzled float4 LDS mirror.
// Final dump of the LDS mirror to d_ws (packed xyz for ballgroup).
// ---------------------------------------------------------------------------
__global__ __launch_bounds__(512) void fps_kernel(const float* __restrict__ xyz,
                                                  float* __restrict__ new_xyz,
                                                  float4* __restrict__ xyz4) {
#pragma clang fp contract(off)
    const int b    = blockIdx.x;
    const int t    = threadIdx.x;
    const int lane = t & 63;
    const int w    = t >> 6;              // wave id, 0..7
    const float* bx = xyz + (size_t)b * NPTS * 3;

    __shared__ float4 pts[NPTS];                    // 128 KB, XOR-swizzled
    __shared__ unsigned long long partial[2][8];

    // thread t owns points j = t*16 + i, i in [0,16): 48 consecutive floats
    v2f px[8], py[8], pz[8], dist[8];
    {
        float f[48];
        float4* fq = (float4*)f;
        const float4* s4 = (const float4*)bx + t * 12;
#pragma unroll
        for (int q = 0; q < 12; ++q) fq[q] = s4[q];
#pragma unroll
        for (int p = 0; p < 8; ++p) {
            px[p] = (v2f){f[6 * p + 0], f[6 * p + 3]};
            py[p] = (v2f){f[6 * p + 1], f[6 * p + 4]};
            pz[p] = (v2f){f[6 * p + 2], f[6 * p + 5]};
            dist[p] = (v2f){1e38f, 1e38f};
        }
#pragma unroll
        for (int i = 0; i < 16; ++i) {
            const int j  = t * 16 + i;
            const int js = j ^ ((j >> 4) & 7);      // bank swizzle
            pts[js] = make_float4(f[3 * i + 0], f[3 * i + 1], f[3 * i + 2], 0.0f);
        }
    }
    __syncthreads();

    // seed: xyz[b, 0]  (swizzle(0) == 0)
    float4 c0 = pts[0];
    float lx = c0.x, ly = c0.y, lz = c0.z;
    if (t == 0) {
        float* o = new_xyz + (size_t)b * NPOINT * 3;
        o[0] = lx; o[1] = ly; o[2] = lz;
    }

    for (int s = 1; s < NPOINT; ++s) {
        // --- packed update + serial inline argmax over 16 points ---
        const v2f lx2 = (v2f){lx, lx};
        const v2f ly2 = (v2f){ly, ly};
        const v2f lz2 = (v2f){lz, lz};
        float bestv = -1.0f;
        int   bi    = 0;
#pragma unroll
        for (int p = 0; p < 8; ++p) {
            const v2f dx = pk_sub(px[p], lx2);
            const v2f dy = pk_sub(py[p], ly2);
            const v2f dz = pk_sub(pz[p], lz2);
            // (dx*dx + dy*dy) + dz*dz — same association as reference, no fma
            const v2f d2 = pk_add(pk_add(pk_mul(dx, dx), pk_mul(dy, dy)),
                                  pk_mul(dz, dz));
            const float d0 = fminf(dist[p].x, d2.x);
            const float d1 = fminf(dist[p].y, d2.y);
            dist[p] = (v2f){d0, d1};
            if (d0 > bestv) { bestv = d0; bi = 2 * p; }     // strict > keeps lowest i
            if (d1 > bestv) { bestv = d1; bi = 2 * p + 1; }
        }
        const int besti = (t << 4) + bi;

        // --- wave64 max via DPP (no LDS) ---
        float v = bestv;
        v = dpp_max_step<DPP_ROW_SHR(1)>(v);
        v = dpp_max_step<DPP_ROW_SHR(2)>(v);
        v = dpp_max_step<DPP_ROW_SHR(4)>(v);
        v = dpp_max_step<DPP_ROW_SHR(8)>(v);
        v = dpp_max_step<DPP_BCAST15>(v);
        v = dpp_max_step<DPP_BCAST31>(v);
        const float smax = __int_as_float(__builtin_amdgcn_readlane(__float_as_int(v), 63));

        // leader lane (lowest lane holding the max == lowest index) writes partial
        const unsigned long long m = __ballot(bestv == smax);
        const int par = s & 1;
        if (lane == (int)__builtin_ctzll(m)) {
            partial[par][w] = ((unsigned long long)__float_as_uint(smax) << 32)
                              | (unsigned)(~besti);
        }
        __syncthreads();

        // --- all lanes scan the 8 partials: depth-3 u64 max tree ---
        const unsigned long long* P = partial[par];
        const unsigned long long a0 = P[0], a1 = P[1], a2 = P[2], a3 = P[3];
        const unsigned long long a4 = P[4], a5 = P[5], a6 = P[6], a7 = P[7];
        const unsigned long long bp =
            u64max(u64max(u64max(a0, a1), u64max(a2, a3)),
                   u64max(u64max(a4, a5), u64max(a6, a7)));
        const int idx = (int)(~(unsigned)bp);
        const int js  = idx ^ ((idx >> 4) & 7);
        const float4 cw = pts[js];              // uniform -> broadcast b128
        lx = cw.x; ly = cw.y; lz = cw.z;
        if (t == 0) {
            float* o = new_xyz + ((size_t)b * NPOINT + s) * 3;
            o[0] = lx; o[1] = ly; o[2] = lz;
        }
    }

    // --- dump packed float4 xyz to workspace (coalesced 1KB/wave stores) ---
    float4* wb = xyz4 + (size_t)b * NPTS;
#pragma unroll
    for (int q = 0; q < 16; ++q) {
        const int p  = q * 512 + t;
        const int ps = p ^ ((p >> 4) & 7);      // un-swizzle
        wb[p] = pts[ps];
    }
}

// ---------------------------------------------------------------------------
// Kernel 2: ball query + grouping — UNCHANGED (best measured shape).
// One block (4 waves) per center; wave r scans quarter r in 8 superrounds
// of 256 pts with coalesced float4 loads from the packed xyz4 workspace.
// Quarter results prefix-merged (exact first-32-ascending + first-hit pad).
// Gather: 256 threads over 32x35, coalesced stores.
// ---------------------------------------------------------------------------
__global__ __launch_bounds__(256) void ballgroup_kernel(const float4* __restrict__ xyz4,
                                                        const float* __restrict__ points,
                                                        const float* __restrict__ new_xyz,
                                                        float* __restrict__ out) {
#pragma clang fp contract(off)
    const int tid  = threadIdx.x;
    const int lane = tid & 63;
    const int r    = tid >> 6;            // wave id = quarter id, 0..3
    const int gw   = blockIdx.x;          // center id, 0..8191
    const int b    = gw >> 10;

    const float4* bx4 = xyz4 + (size_t)b * NPTS;
    const float*  cen = new_xyz + (size_t)gw * 3;
    const float cx = cen[0], cy = cen[1], cz = cen[2];

    __shared__ int qidx[4][NSAMPLE];
    __shared__ int qcnt[4];

    // --- scan this wave's quarter: 2048 pts, 8 superrounds of 256 ---
    int k = 0;
    const int qbase = r << 11;
    for (int base = qbase; base < qbase + 2048; base += 256) {
        // phase 1: hoist 4 coalesced dwordx4 loads (independent)
        float4 p4[4];
#pragma unroll
        for (int u = 0; u < 4; ++u) p4[u] = bx4[base + u * 64 + lane];
        // phase 2: distances + masks (no memory)
        bool in[4];
#pragma unroll
        for (int u = 0; u < 4; ++u) {
            const float dx = p4[u].x - cx;
            const float dy = p4[u].y - cy;
            const float dz = p4[u].z - cz;
            const float d2 = (dx * dx + dy * dy) + dz * dz;   // contract off
            in[u] = d2 < R2;
        }
        // phase 3: serial bookkeeping (no loads on chain)
#pragma unroll
        for (int u = 0; u < 4; ++u) {
            const unsigned long long mu = __ballot(in[u]);
            const int pre = __popcll(mu & ((1ull << lane) - 1ull));
            if (in[u] && (k + pre) < NSAMPLE) qidx[r][k + pre] = base + u * 64 + lane;
            k += __popcll(mu);
        }
        if (k >= NSAMPLE) break;          // one exit check per superround
    }
    if (k > NSAMPLE) k = NSAMPLE;
    if (lane == 0) qcnt[r] = k;
    __syncthreads();

    // --- prefix-merge: first NSAMPLE of the concatenated quarters ---
    const int c0n = qcnt[0], c1n = qcnt[1], c2n = qcnt[2], c3n = qcnt[3];
    const int o1 = c0n, o2 = c0n + c1n, o3 = o2 + c2n;
    const int total = o3 + c3n;
    const int kk = total < NSAMPLE ? total : NSAMPLE;
    // first hit overall = first entry of the first nonempty quarter
    // (center's own point has d2==0, so total >= 1 always)
    const int r0 = (c0n > 0) ? 0 : (c1n > 0) ? 1 : (c2n > 0) ? 2 : 3;
    const int firstIdx = qidx[r0][0];

    // --- gather: 32x35 output elems across 256 threads, coalesced ---
    float*       o    = out + (size_t)gw * NSAMPLE * OUTC;
    const float* prow = points + (size_t)b * NPTS * CHANC;
    for (int e = tid; e < NSAMPLE * OUTC; e += 256) {
        const int s = e / OUTC;
        const int c = e - s * OUTC;
        int j;
        if (s < kk) {
            const int rr  = (int)(s >= o1) + (int)(s >= o2) + (int)(s >= o3);
            const int off = (rr == 0) ? 0 : (rr == 1) ? o1 : (rr == 2) ? o2 : o3;
            j = qidx[rr][s - off];
        } else {
            j = firstIdx;
        }
        float v;
        if (c < 3) {
            const float4 pj = bx4[j];
            const float pv = (c == 0) ? pj.x : (c == 1) ? pj.y : pj.z;
            const float cc = (c == 0) ? cx : (c == 1) ? cy : cz;
            v = pv - cc;
        } else {
            v = prow[j * CHANC + (c - 3)];
        }
        o[e] = v;   // consecutive lanes -> consecutive addresses (coalesced)
    }
}

// ---------------------------------------------------------------------------
extern "C" void kernel_launch(void* const* d_in, const int* in_sizes, int n_in,
                              void* d_out, int out_size, void* d_ws, size_t ws_size,
                              hipStream_t stream) {
    const float* xyz    = (const float*)d_in[0];   // (8, 8192, 3)  fp32
    const float* points = (const float*)d_in[1];   // (8, 8192, 32) fp32
    float* new_xyz    = (float*)d_out;                         // (8,1024,3)
    float* new_points = new_xyz + (size_t)BATCH * NPOINT * 3;  // (8,1024,32,35)
    float4* xyz4      = (float4*)d_ws;                         // 512 KB packed

    fps_kernel<<<BATCH, 512, 0, stream>>>(xyz, new_xyz, xyz4);
    ballgroup_kernel<<<BATCH * NPOINT, 256, 0, stream>>>(xyz4, points, new_xyz, new_points);
}

// Round 3
// 1017.566 us; speedup vs baseline: 2.5504x; 1.0578x over previous
//
#include <hip/hip_runtime.h>

#define BATCH   8
#define NPTS    8192
#define NPOINT  1024
#define NSAMPLE 32
#define CHANC   32
#define OUTC    35          // 3 xyz + 32 point channels
#define R2      0.0625f     // 0.25^2

#define NBLK    256                    // 1 block/CU (LDS-forced), cooperative
#define NTHR    512
#define NJOBS   (BATCH * NPOINT / 2)   // 4096 jobs x 2 centers

typedef float v2f __attribute__((ext_vector_type(2)));
typedef unsigned long long u64;
typedef unsigned int u32;

// DPP helpers --------------------------------------------------------------
template <int CTRL>
__device__ __forceinline__ float dpp_max_step(float v) {
    int r = __builtin_amdgcn_update_dpp(__float_as_int(v), __float_as_int(v),
                                        CTRL, 0xf, 0xf, false);
    return fmaxf(v, __int_as_float(r));
}
#define DPP_ROW_SHR(n)  (0x110 | (n))
#define DPP_BCAST15     0x142
#define DPP_BCAST31     0x143

__device__ __forceinline__ u64 u64max(u64 a, u64 b) { return a > b ? a : b; }

// ---------------------------------------------------------------------------
// Fused persistent kernel (cooperative, 256 blocks x 512 thr, 1/CU).
//  Blocks 0..7   : FPS, r0-verbatim compute path (885 µs structure: packed
//                  update, serial argmax, DPP wave max, ballot leader, one
//                  barrier/iter parity dbuf, u64 tree, swizzled LDS mirror).
//                  t==0 additionally publishes each winner center (b,s) as
//                  three tagged u64 words (tag=gw+1 | coord bits) via
//                  fire-and-forget agent-scope atomic stores. Each word is
//                  self-validating -> no release fence; each slot written
//                  exactly once; the vmcnt drain at the next __syncthreads
//                  hides under the ~700cy update phase.
//  Blocks 8..255 : ballgroup workers. Grab 2-center jobs from a global
//                  counter, poll the 3 slot words (wave-uniform address,
//                  s_sleep backoff), then r11 quarter-scan / prefix-merge /
//                  gather reading RAW read-only xyz (no coherence hazard;
//                  scan cost hidden under the fps window).
//  Net effect: ballgroup (~105 µs serial in r0) overlaps fps almost fully.
// ---------------------------------------------------------------------------
__global__ __launch_bounds__(NTHR) void fused_kernel(
        const float* __restrict__ xyz,
        const float* __restrict__ points,
        float* __restrict__ new_xyz,
        float* __restrict__ out,
        u64* __restrict__ slots,
        u32* __restrict__ counter)
{
#pragma clang fp contract(off)
    __shared__ float4 pts[NPTS];                    // 128 KB, XOR-swizzled (fps)
    __shared__ u64 partial[2][8];                   // fps
    __shared__ int qidx[2][4][NSAMPLE];             // worker: 2 centers
    __shared__ int qcnt[2][4];
    __shared__ int jobsh;

    const int blk  = blockIdx.x;
    const int t    = threadIdx.x;
    const int lane = t & 63;

    if (blk < BATCH) {
        // ================= FPS role =================
        const int b = blk;
        const int w = t >> 6;                       // wave id, 0..7
        const float* bx = xyz + (size_t)b * NPTS * 3;
        u64* bslot = slots + (size_t)b * NPOINT * 3;

        // thread t owns points j = t*16 + i, i in [0,16): 48 consecutive floats
        v2f px[8], py[8], pz[8], dist[8];
        {
            float f[48];
            float4* fq = (float4*)f;
            const float4* s4 = (const float4*)bx + t * 12;
#pragma unroll
            for (int q = 0; q < 12; ++q) fq[q] = s4[q];
#pragma unroll
            for (int p = 0; p < 8; ++p) {
                px[p] = (v2f){f[6 * p + 0], f[6 * p + 3]};
                py[p] = (v2f){f[6 * p + 1], f[6 * p + 4]};
                pz[p] = (v2f){f[6 * p + 2], f[6 * p + 5]};
                dist[p] = (v2f){1e38f, 1e38f};
            }
#pragma unroll
            for (int i = 0; i < 16; ++i) {
                const int j  = t * 16 + i;
                const int js = j ^ ((j >> 4) & 7);  // bank swizzle
                pts[js] = make_float4(f[3 * i + 0], f[3 * i + 1], f[3 * i + 2], 0.0f);
            }
        }
        __syncthreads();

        // seed: xyz[b, 0]  (swizzle(0) == 0)
        float4 c0 = pts[0];
        float lx = c0.x, ly = c0.y, lz = c0.z;
        if (t == 0) {
            float* o = new_xyz + (size_t)b * NPOINT * 3;
            o[0] = lx; o[1] = ly; o[2] = lz;
            const u64 tag = (u64)(u32)(b * NPOINT + 1);   // gw+1, s=0
            __hip_atomic_store(&bslot[0], (tag << 32) | (u64)__float_as_uint(lx),
                               __ATOMIC_RELAXED, __HIP_MEMORY_SCOPE_AGENT);
            __hip_atomic_store(&bslot[1], (tag << 32) | (u64)__float_as_uint(ly),
                               __ATOMIC_RELAXED, __HIP_MEMORY_SCOPE_AGENT);
            __hip_atomic_store(&bslot[2], (tag << 32) | (u64)__float_as_uint(lz),
                               __ATOMIC_RELAXED, __HIP_MEMORY_SCOPE_AGENT);
        }

        for (int s = 1; s < NPOINT; ++s) {
            // --- packed update + serial inline argmax over 16 points ---
            const v2f lx2 = (v2f){lx, lx};
            const v2f ly2 = (v2f){ly, ly};
            const v2f lz2 = (v2f){lz, lz};
            float bestv = -1.0f;
            int   bi    = 0;
#pragma unroll
            for (int p = 0; p < 8; ++p) {
                const v2f dx = px[p] - lx2;
                const v2f dy = py[p] - ly2;
                const v2f dz = pz[p] - lz2;
                const v2f d2 = (dx * dx + dy * dy) + dz * dz;   // contract off -> exact
                const float d0 = fminf(dist[p].x, d2.x);
                const float d1 = fminf(dist[p].y, d2.y);
                dist[p] = (v2f){d0, d1};
                if (d0 > bestv) { bestv = d0; bi = 2 * p; }     // strict > keeps lowest i
                if (d1 > bestv) { bestv = d1; bi = 2 * p + 1; }
            }
            const int besti = (t << 4) + bi;

            // --- wave64 max via DPP (no LDS) ---
            float v = bestv;
            v = dpp_max_step<DPP_ROW_SHR(1)>(v);
            v = dpp_max_step<DPP_ROW_SHR(2)>(v);
            v = dpp_max_step<DPP_ROW_SHR(4)>(v);
            v = dpp_max_step<DPP_ROW_SHR(8)>(v);
            v = dpp_max_step<DPP_BCAST15>(v);
            v = dpp_max_step<DPP_BCAST31>(v);
            const float smax = __int_as_float(__builtin_amdgcn_readlane(__float_as_int(v), 63));

            // leader lane (lowest lane holding the max == lowest index) writes partial
            const u64 m   = __ballot(bestv == smax);
            const int par = s & 1;
            if (lane == (int)__builtin_ctzll(m)) {
                partial[par][w] = ((u64)__float_as_uint(smax) << 32)
                                  | (unsigned)(~besti);
            }
            __syncthreads();

            // --- all lanes scan the 8 partials: depth-3 u64 max tree ---
            const u64* P = partial[par];
            const u64 a0 = P[0], a1 = P[1], a2 = P[2], a3 = P[3];
            const u64 a4 = P[4], a5 = P[5], a6 = P[6], a7 = P[7];
            const u64 bp =
                u64max(u64max(u64max(a0, a1), u64max(a2, a3)),
                       u64max(u64max(a4, a5), u64max(a6, a7)));
            const int idx = (int)(~(unsigned)bp);
            const int js  = idx ^ ((idx >> 4) & 7);
            const float4 cw = pts[js];              // uniform -> broadcast b128
            lx = cw.x; ly = cw.y; lz = cw.z;
            if (t == 0) {
                float* o = new_xyz + ((size_t)b * NPOINT + s) * 3;
                o[0] = lx; o[1] = ly; o[2] = lz;
                // publish center (b,s): fire-and-forget tagged words
                const u64 tag = (u64)(u32)(b * NPOINT + s + 1);
                __hip_atomic_store(&bslot[3 * s + 0], (tag << 32) | (u64)__float_as_uint(lx),
                                   __ATOMIC_RELAXED, __HIP_MEMORY_SCOPE_AGENT);
                __hip_atomic_store(&bslot[3 * s + 1], (tag << 32) | (u64)__float_as_uint(ly),
                                   __ATOMIC_RELAXED, __HIP_MEMORY_SCOPE_AGENT);
                __hip_atomic_store(&bslot[3 * s + 2], (tag << 32) | (u64)__float_as_uint(lz),
                                   __ATOMIC_RELAXED, __HIP_MEMORY_SCOPE_AGENT);
            }
        }
    } else {
        // ================= worker role =================
        for (;;) {
            if (t == 0) jobsh = (int)atomicAdd(counter, 1u);
            __syncthreads();                        // also fences qidx reuse
            const int job = jobsh;
            if (job >= NJOBS) break;                // uniform exit

            const int half = t >> 8;                // 0: center A, 1: center B
            const int gw   = job * 2 + half;        // center id
            const int bb   = gw >> 10;
            const int r    = (t >> 6) & 3;          // quarter within center group

            // --- wait for center coords (3 tagged words, uniform-addr poll) ---
            const u32 tag = (u32)(gw + 1);
            u64* sl = slots + (size_t)gw * 3;
            u64 w0, w1, w2;
            for (;;) {
                w0 = __hip_atomic_load(&sl[0], __ATOMIC_RELAXED, __HIP_MEMORY_SCOPE_AGENT);
                w1 = __hip_atomic_load(&sl[1], __ATOMIC_RELAXED, __HIP_MEMORY_SCOPE_AGENT);
                w2 = __hip_atomic_load(&sl[2], __ATOMIC_RELAXED, __HIP_MEMORY_SCOPE_AGENT);
                if ((u32)(w0 >> 32) == tag && (u32)(w1 >> 32) == tag &&
                    (u32)(w2 >> 32) == tag) break;
                __builtin_amdgcn_s_sleep(8);
            }
            const float cx = __uint_as_float((u32)w0);
            const float cy = __uint_as_float((u32)w1);
            const float cz = __uint_as_float((u32)w2);

            // --- scan this wave's quarter: 2048 pts, 8 superrounds of 256 ---
            const float* bxr = xyz + (size_t)bb * NPTS * 3;
            int k = 0;
            const int qbase = r << 11;
            for (int base = qbase; base < qbase + 2048; base += 256) {
                float qx[4], qy[4], qz[4];
#pragma unroll
                for (int u = 0; u < 4; ++u) {
                    const int j = base + u * 64 + lane;
                    qx[u] = bxr[3 * j + 0];
                    qy[u] = bxr[3 * j + 1];
                    qz[u] = bxr[3 * j + 2];
                }
                bool in[4];
#pragma unroll
                for (int u = 0; u < 4; ++u) {
                    const float dx = qx[u] - cx;
                    const float dy = qy[u] - cy;
                    const float dz = qz[u] - cz;
                    const float d2 = (dx * dx + dy * dy) + dz * dz;   // contract off
                    in[u] = d2 < R2;
                }
#pragma unroll
                for (int u = 0; u < 4; ++u) {
                    const u64 mu = __ballot(in[u]);
                    const int pre = __popcll(mu & ((1ull << lane) - 1ull));
                    if (in[u] && (k + pre) < NSAMPLE) qidx[half][r][k + pre] = base + u * 64 + lane;
                    k += __popcll(mu);
                }
                if (k >= NSAMPLE) break;            // one exit check per superround
            }
            if (k > NSAMPLE) k = NSAMPLE;
            if (lane == 0) qcnt[half][r] = k;
            __syncthreads();

            // --- prefix-merge: first NSAMPLE of the concatenated quarters ---
            const int c0n = qcnt[half][0], c1n = qcnt[half][1];
            const int c2n = qcnt[half][2], c3n = qcnt[half][3];
            const int o1 = c0n, o2 = c0n + c1n, o3 = o2 + c2n;
            const int total = o3 + c3n;
            const int kk = total < NSAMPLE ? total : NSAMPLE;
            const int rq = (c0n > 0) ? 0 : (c1n > 0) ? 1 : (c2n > 0) ? 2 : 3;
            const int firstIdx = qidx[half][rq][0];

            // --- gather: 32x35 output elems across 256 threads, coalesced ---
            float*       o    = out + (size_t)gw * NSAMPLE * OUTC;
            const float* prow = points + (size_t)bb * NPTS * CHANC;
            const int t256 = t & 255;
            for (int e = t256; e < NSAMPLE * OUTC; e += 256) {
                const int sI = e / OUTC;
                const int c  = e - sI * OUTC;
                int j;
                if (sI < kk) {
                    const int rr  = (int)(sI >= o1) + (int)(sI >= o2) + (int)(sI >= o3);
                    const int off = (rr == 0) ? 0 : (rr == 1) ? o1 : (rr == 2) ? o2 : o3;
                    j = qidx[half][rr][sI - off];
                } else {
                    j = firstIdx;
                }
                float v;
                if (c < 3) {
                    const float pv = bxr[3 * j + c];
                    const float cc = (c == 0) ? cx : (c == 1) ? cy : cz;
                    v = pv - cc;
                } else {
                    v = prow[j * CHANC + (c - 3)];
                }
                o[e] = v;   // consecutive lanes -> consecutive addresses (coalesced)
            }
            // loop: next job's top barrier separates qidx reuse
        }
    }
}

// ---------------------------------------------------------------------------
extern "C" void kernel_launch(void* const* d_in, const int* in_sizes, int n_in,
                              void* d_out, int out_size, void* d_ws, size_t ws_size,
                              hipStream_t stream) {
    const float* xyz    = (const float*)d_in[0];   // (8, 8192, 3)  fp32
    const float* points = (const float*)d_in[1];   // (8, 8192, 32) fp32
    float* new_xyz    = (float*)d_out;                         // (8,1024,3)
    float* new_points = new_xyz + (size_t)BATCH * NPOINT * 3;  // (8,1024,32,35)

    u64* slots   = (u64*)d_ws;                                 // 8192 x 3 tagged words
    u32* counter = (u32*)((char*)d_ws + (size_t)BATCH * NPOINT * 3 * sizeof(u64));

    // kill stale tags + job counter from previous graph replay (~192 KB)
    hipMemsetAsync(d_ws, 0, (size_t)BATCH * NPOINT * 3 * sizeof(u64) + 64, stream);

    void* args[] = { (void*)&xyz, (void*)&points, (void*)&new_xyz,
                     (void*)&new_points, (void*)&slots, (void*)&counter };
    hipLaunchCooperativeKernel((void*)fused_kernel, dim3(NBLK), dim3(NTHR),
                               args, 0, stream);
}

// Round 4
// 1017.251 us; speedup vs baseline: 2.5512x; 1.0003x over previous
//
#include <hip/hip_runtime.h>

#define BATCH   8
#define NPTS    8192
#define NPOINT  1024
#define NSAMPLE 32
#define CHANC   32
#define OUTC    35          // 3 xyz + 32 point channels
#define R2      0.0625f     // 0.25^2

#define NBLK    256                    // 1 block/CU (LDS-forced), cooperative
#define NTHR    512
#define NJOBS   (BATCH * NPOINT / 2)   // 4096 jobs x 2 centers

typedef float v2f __attribute__((ext_vector_type(2)));
typedef unsigned long long u64;
typedef unsigned int u32;

// DPP helpers --------------------------------------------------------------
template <int CTRL>
__device__ __forceinline__ float dpp_max_step(float v) {
    int r = __builtin_amdgcn_update_dpp(__float_as_int(v), __float_as_int(v),
                                        CTRL, 0xf, 0xf, false);
    return fmaxf(v, __int_as_float(r));
}
#define DPP_ROW_SHR(n)  (0x110 | (n))
#define DPP_BCAST15     0x142
#define DPP_BCAST31     0x143

__device__ __forceinline__ u64 u64max(u64 a, u64 b) { return a > b ? a : b; }

// Barrier that drains ONLY LDS (lgkmcnt) — NOT vmcnt. The FPS loop's only
// outstanding VMEM ops are fire-and-forget tagged publishes (self-validating,
// written once, arbitrary delay safe) and new_xyz output stores (read only
// after kernel end). __syncthreads() would drain vmcnt(0) and eat the sc1
// LLC-ack latency every iteration (R3: +65 µs). "memory" clobber keeps the
// leader's ds_write above and the partial[] reads below.
__device__ __forceinline__ void barrier_lds_only() {
    asm volatile("s_waitcnt lgkmcnt(0)\n\ts_barrier" ::: "memory");
}

// ---------------------------------------------------------------------------
// Fused persistent kernel (cooperative, 256 blocks x 512 thr, 1/CU).
//  Blocks 0..7   : FPS, r0-verbatim compute path (885 µs structure) with the
//                  in-loop barrier replaced by barrier_lds_only(). t==0
//                  publishes each winner center (b,s) as three tagged u64
//                  words (tag=gw+1 | coord bits) via fire-and-forget agent-
//                  scope atomic stores; acks never block the loop now.
//  Blocks 8..255 : ballgroup workers. Grab 2-center jobs from a global
//                  counter, poll the 3 slot words (wave-uniform address,
//                  s_sleep(32) backoff), then r11 quarter-scan / prefix-merge
//                  / gather reading RAW read-only xyz (no coherence hazard;
//                  scan cost hidden under the fps window).
// ---------------------------------------------------------------------------
__global__ __launch_bounds__(NTHR) void fused_kernel(
        const float* __restrict__ xyz,
        const float* __restrict__ points,
        float* __restrict__ new_xyz,
        float* __restrict__ out,
        u64* __restrict__ slots,
        u32* __restrict__ counter)
{
#pragma clang fp contract(off)
    __shared__ float4 pts[NPTS];                    // 128 KB, XOR-swizzled (fps)
    __shared__ u64 partial[2][8];                   // fps
    __shared__ int qidx[2][4][NSAMPLE];             // worker: 2 centers
    __shared__ int qcnt[2][4];
    __shared__ int jobsh;

    const int blk  = blockIdx.x;
    const int t    = threadIdx.x;
    const int lane = t & 63;

    if (blk < BATCH) {
        // ================= FPS role =================
        const int b = blk;
        const int w = t >> 6;                       // wave id, 0..7
        const float* bx = xyz + (size_t)b * NPTS * 3;
        u64* bslot = slots + (size_t)b * NPOINT * 3;

        // thread t owns points j = t*16 + i, i in [0,16): 48 consecutive floats
        v2f px[8], py[8], pz[8], dist[8];
        {
            float f[48];
            float4* fq = (float4*)f;
            const float4* s4 = (const float4*)bx + t * 12;
#pragma unroll
            for (int q = 0; q < 12; ++q) fq[q] = s4[q];
#pragma unroll
            for (int p = 0; p < 8; ++p) {
                px[p] = (v2f){f[6 * p + 0], f[6 * p + 3]};
                py[p] = (v2f){f[6 * p + 1], f[6 * p + 4]};
                pz[p] = (v2f){f[6 * p + 2], f[6 * p + 5]};
                dist[p] = (v2f){1e38f, 1e38f};
            }
#pragma unroll
            for (int i = 0; i < 16; ++i) {
                const int j  = t * 16 + i;
                const int js = j ^ ((j >> 4) & 7);  // bank swizzle
                pts[js] = make_float4(f[3 * i + 0], f[3 * i + 1], f[3 * i + 2], 0.0f);
            }
        }
        __syncthreads();

        // seed: xyz[b, 0]  (swizzle(0) == 0)
        float4 c0 = pts[0];
        float lx = c0.x, ly = c0.y, lz = c0.z;
        if (t == 0) {
            float* o = new_xyz + (size_t)b * NPOINT * 3;
            o[0] = lx; o[1] = ly; o[2] = lz;
            const u64 tag = (u64)(u32)(b * NPOINT + 1);   // gw+1, s=0
            __hip_atomic_store(&bslot[0], (tag << 32) | (u64)__float_as_uint(lx),
                               __ATOMIC_RELAXED, __HIP_MEMORY_SCOPE_AGENT);
            __hip_atomic_store(&bslot[1], (tag << 32) | (u64)__float_as_uint(ly),
                               __ATOMIC_RELAXED, __HIP_MEMORY_SCOPE_AGENT);
            __hip_atomic_store(&bslot[2], (tag << 32) | (u64)__float_as_uint(lz),
                               __ATOMIC_RELAXED, __HIP_MEMORY_SCOPE_AGENT);
        }

        for (int s = 1; s < NPOINT; ++s) {
            // --- packed update + serial inline argmax over 16 points ---
            const v2f lx2 = (v2f){lx, lx};
            const v2f ly2 = (v2f){ly, ly};
            const v2f lz2 = (v2f){lz, lz};
            float bestv = -1.0f;
            int   bi    = 0;
#pragma unroll
            for (int p = 0; p < 8; ++p) {
                const v2f dx = px[p] - lx2;
                const v2f dy = py[p] - ly2;
                const v2f dz = pz[p] - lz2;
                const v2f d2 = (dx * dx + dy * dy) + dz * dz;   // contract off -> exact
                const float d0 = fminf(dist[p].x, d2.x);
                const float d1 = fminf(dist[p].y, d2.y);
                dist[p] = (v2f){d0, d1};
                if (d0 > bestv) { bestv = d0; bi = 2 * p; }     // strict > keeps lowest i
                if (d1 > bestv) { bestv = d1; bi = 2 * p + 1; }
            }
            const int besti = (t << 4) + bi;

            // --- wave64 max via DPP (no LDS) ---
            float v = bestv;
            v = dpp_max_step<DPP_ROW_SHR(1)>(v);
            v = dpp_max_step<DPP_ROW_SHR(2)>(v);
            v = dpp_max_step<DPP_ROW_SHR(4)>(v);
            v = dpp_max_step<DPP_ROW_SHR(8)>(v);
            v = dpp_max_step<DPP_BCAST15>(v);
            v = dpp_max_step<DPP_BCAST31>(v);
            const float smax = __int_as_float(__builtin_amdgcn_readlane(__float_as_int(v), 63));

            // leader lane (lowest lane holding the max == lowest index) writes partial
            const u64 m   = __ballot(bestv == smax);
            const int par = s & 1;
            if (lane == (int)__builtin_ctzll(m)) {
                partial[par][w] = ((u64)__float_as_uint(smax) << 32)
                                  | (unsigned)(~besti);
            }
            barrier_lds_only();                     // drains LDS only, not vmcnt

            // --- all lanes scan the 8 partials: depth-3 u64 max tree ---
            const u64* P = partial[par];
            const u64 a0 = P[0], a1 = P[1], a2 = P[2], a3 = P[3];
            const u64 a4 = P[4], a5 = P[5], a6 = P[6], a7 = P[7];
            const u64 bp =
                u64max(u64max(u64max(a0, a1), u64max(a2, a3)),
                       u64max(u64max(a4, a5), u64max(a6, a7)));
            const int idx = (int)(~(unsigned)bp);
            const int js  = idx ^ ((idx >> 4) & 7);
            const float4 cw = pts[js];              // uniform -> broadcast b128
            lx = cw.x; ly = cw.y; lz = cw.z;
            if (t == 0) {
                float* o = new_xyz + ((size_t)b * NPOINT + s) * 3;
                o[0] = lx; o[1] = ly; o[2] = lz;
                // publish center (b,s): fire-and-forget tagged words
                const u64 tag = (u64)(u32)(b * NPOINT + s + 1);
                __hip_atomic_store(&bslot[3 * s + 0], (tag << 32) | (u64)__float_as_uint(lx),
                                   __ATOMIC_RELAXED, __HIP_MEMORY_SCOPE_AGENT);
                __hip_atomic_store(&bslot[3 * s + 1], (tag << 32) | (u64)__float_as_uint(ly),
                                   __ATOMIC_RELAXED, __HIP_MEMORY_SCOPE_AGENT);
                __hip_atomic_store(&bslot[3 * s + 2], (tag << 32) | (u64)__float_as_uint(lz),
                                   __ATOMIC_RELAXED, __HIP_MEMORY_SCOPE_AGENT);
            }
        }
    } else {
        // ================= worker role =================
        for (;;) {
            if (t == 0) jobsh = (int)atomicAdd(counter, 1u);
            __syncthreads();                        // also fences qidx reuse
            const int job = jobsh;
            if (job >= NJOBS) break;                // uniform exit

            const int half = t >> 8;                // 0: center A, 1: center B
            const int gw   = job * 2 + half;        // center id
            const int bb   = gw >> 10;
            const int r    = (t >> 6) & 3;          // quarter within center group

            // --- wait for center coords (3 tagged words, uniform-addr poll) ---
            const u32 tag = (u32)(gw + 1);
            u64* sl = slots + (size_t)gw * 3;
            u64 w0, w1, w2;
            for (;;) {
                w0 = __hip_atomic_load(&sl[0], __ATOMIC_RELAXED, __HIP_MEMORY_SCOPE_AGENT);
                w1 = __hip_atomic_load(&sl[1], __ATOMIC_RELAXED, __HIP_MEMORY_SCOPE_AGENT);
                w2 = __hip_atomic_load(&sl[2], __ATOMIC_RELAXED, __HIP_MEMORY_SCOPE_AGENT);
                if ((u32)(w0 >> 32) == tag && (u32)(w1 >> 32) == tag &&
                    (u32)(w2 >> 32) == tag) break;
                __builtin_amdgcn_s_sleep(32);
            }
            const float cx = __uint_as_float((u32)w0);
            const float cy = __uint_as_float((u32)w1);
            const float cz = __uint_as_float((u32)w2);

            // --- scan this wave's quarter: 2048 pts, 8 superrounds of 256 ---
            const float* bxr = xyz + (size_t)bb * NPTS * 3;
            int k = 0;
            const int qbase = r << 11;
            for (int base = qbase; base < qbase + 2048; base += 256) {
                float qx[4], qy[4], qz[4];
#pragma unroll
                for (int u = 0; u < 4; ++u) {
                    const int j = base + u * 64 + lane;
                    qx[u] = bxr[3 * j + 0];
                    qy[u] = bxr[3 * j + 1];
                    qz[u] = bxr[3 * j + 2];
                }
                bool in[4];
#pragma unroll
                for (int u = 0; u < 4; ++u) {
                    const float dx = qx[u] - cx;
                    const float dy = qy[u] - cy;
                    const float dz = qz[u] - cz;
                    const float d2 = (dx * dx + dy * dy) + dz * dz;   // contract off
                    in[u] = d2 < R2;
                }
#pragma unroll
                for (int u = 0; u < 4; ++u) {
                    const u64 mu = __ballot(in[u]);
                    const int pre = __popcll(mu & ((1ull << lane) - 1ull));
                    if (in[u] && (k + pre) < NSAMPLE) qidx[half][r][k + pre] = base + u * 64 + lane;
                    k += __popcll(mu);
                }
                if (k >= NSAMPLE) break;            // one exit check per superround
            }
            if (k > NSAMPLE) k = NSAMPLE;
            if (lane == 0) qcnt[half][r] = k;
            __syncthreads();

            // --- prefix-merge: first NSAMPLE of the concatenated quarters ---
            const int c0n = qcnt[half][0], c1n = qcnt[half][1];
            const int c2n = qcnt[half][2], c3n = qcnt[half][3];
            const int o1 = c0n, o2 = c0n + c1n, o3 = o2 + c2n;
            const int total = o3 + c3n;
            const int kk = total < NSAMPLE ? total : NSAMPLE;
            const int rq = (c0n > 0) ? 0 : (c1n > 0) ? 1 : (c2n > 0) ? 2 : 3;
            const int firstIdx = qidx[half][rq][0];

            // --- gather: 32x35 output elems across 256 threads, coalesced ---
            float*       o    = out + (size_t)gw * NSAMPLE * OUTC;
            const float* prow = points + (size_t)bb * NPTS * CHANC;
            const int t256 = t & 255;
            for (int e = t256; e < NSAMPLE * OUTC; e += 256) {
                const int sI = e / OUTC;
                const int c  = e - sI * OUTC;
                int j;
                if (sI < kk) {
                    const int rr  = (int)(sI >= o1) + (int)(sI >= o2) + (int)(sI >= o3);
                    const int off = (rr == 0) ? 0 : (rr == 1) ? o1 : (rr == 2) ? o2 : o3;
                    j = qidx[half][rr][sI - off];
                } else {
                    j = firstIdx;
                }
                float v;
                if (c < 3) {
                    const float pv = bxr[3 * j + c];
                    const float cc = (c == 0) ? cx : (c == 1) ? cy : cz;
                    v = pv - cc;
                } else {
                    v = prow[j * CHANC + (c - 3)];
                }
                o[e] = v;   // consecutive lanes -> consecutive addresses (coalesced)
            }
            // loop: next job's top barrier separates qidx reuse
        }
    }
}

// ---------------------------------------------------------------------------
extern "C" void kernel_launch(void* const* d_in, const int* in_sizes, int n_in,
                              void* d_out, int out_size, void* d_ws, size_t ws_size,
                              hipStream_t stream) {
    const float* xyz    = (const float*)d_in[0];   // (8, 8192, 3)  fp32
    const float* points = (const float*)d_in[1];   // (8, 8192, 32) fp32
    float* new_xyz    = (float*)d_out;                         // (8,1024,3)
    float* new_points = new_xyz + (size_t)BATCH * NPOINT * 3;  // (8,1024,32,35)

    u64* slots   = (u64*)d_ws;                                 // 8192 x 3 tagged words
    u32* counter = (u32*)((char*)d_ws + (size_t)BATCH * NPOINT * 3 * sizeof(u64));

    // kill stale tags + job counter from previous graph replay (~192 KB)
    hipMemsetAsync(d_ws, 0, (size_t)BATCH * NPOINT * 3 * sizeof(u64) + 64, stream);

    void* args[] = { (void*)&xyz, (void*)&points, (void*)&new_xyz,
                     (void*)&new_points, (void*)&slots, (void*)&counter };
    hipLaunchCooperativeKernel((void*)fused_kernel, dim3(NBLK), dim3(NTHR),
                               args, 0, stream);
}

// Round 5
// 982.853 us; speedup vs baseline: 2.6405x; 1.0350x over previous
//
#include <hip/hip_runtime.h>

#define BATCH   8
#define NPTS    8192
#define NPOINT  1024
#define NSAMPLE 32
#define CHANC   32
#define OUTC    35          // 3 xyz + 32 point channels
#define R2      0.0625f     // 0.25^2

#define NBLK    256                    // 1 block/CU (LDS-forced co-residency)
#define NTHR    512
#define NJOBS   (BATCH * NPOINT / 2)   // 4096 jobs x 2 centers

typedef float v2f __attribute__((ext_vector_type(2)));
typedef unsigned long long u64;
typedef unsigned int u32;

// DPP helpers --------------------------------------------------------------
template <int CTRL>
__device__ __forceinline__ float dpp_max_step(float v) {
    int r = __builtin_amdgcn_update_dpp(__float_as_int(v), __float_as_int(v),
                                        CTRL, 0xf, 0xf, false);
    return fmaxf(v, __int_as_float(r));
}
#define DPP_ROW_SHR(n)  (0x110 | (n))
#define DPP_BCAST15     0x142
#define DPP_BCAST31     0x143

__device__ __forceinline__ u64 u64max(u64 a, u64 b) { return a > b ? a : b; }

// Barrier that drains ONLY LDS (lgkmcnt) — NOT vmcnt. The FPS loop's only
// outstanding VMEM ops are fire-and-forget tagged publishes (self-validating,
// written once, arbitrary delay safe) and new_xyz output stores (read only
// after kernel end; HW drains stores at s_endpgm). __syncthreads() would
// drain vmcnt(0) and eat the sc1 LLC-ack latency every iteration (R3/R4).
__device__ __forceinline__ void barrier_lds_only() {
    asm volatile("s_waitcnt lgkmcnt(0)\n\ts_barrier" ::: "memory");
}

// ---------------------------------------------------------------------------
// Fused persistent kernel — PLAIN launch (R5: cooperative launch cost ~70 µs
// dispatch overhead; co-residency is guaranteed by capacity instead: 256
// blocks, 1/CU LDS-forced, so the spin-wait cannot deadlock).
//  Blocks 0..7   : FPS, r0-verbatim compute path, lds-only in-loop barrier.
//                  Winner (b,s) published as three tagged u64 words by lanes
//                  t<3 IN PARALLEL (one 3-lane atomic-store + one 3-lane
//                  new_xyz store per iter — R5: halves wave-0's divergent
//                  tail vs t==0's six serial VMEM ops).
//  Blocks 8..255 : ballgroup workers. Grab 2-center jobs from a global
//                  counter, poll the 3 slot words (wave-uniform address,
//                  s_sleep(32) backoff), then r11 quarter-scan / prefix-merge
//                  / gather reading RAW read-only xyz.
// ---------------------------------------------------------------------------
__global__ __launch_bounds__(NTHR) void fused_kernel(
        const float* __restrict__ xyz,
        const float* __restrict__ points,
        float* __restrict__ new_xyz,
        float* __restrict__ out,
        u64* __restrict__ slots,
        u32* __restrict__ counter)
{
#pragma clang fp contract(off)
    __shared__ float4 pts[NPTS];                    // 128 KB, XOR-swizzled (fps)
    __shared__ u64 partial[2][8];                   // fps
    __shared__ int qidx[2][4][NSAMPLE];             // worker: 2 centers
    __shared__ int qcnt[2][4];
    __shared__ int jobsh;

    const int blk  = blockIdx.x;
    const int t    = threadIdx.x;
    const int lane = t & 63;

    if (blk < BATCH) {
        // ================= FPS role =================
        const int b = blk;
        const int w = t >> 6;                       // wave id, 0..7
        const float* bx = xyz + (size_t)b * NPTS * 3;
        u64* bslot = slots + (size_t)b * NPOINT * 3;
        float* oxyz = new_xyz + (size_t)b * NPOINT * 3;

        // thread t owns points j = t*16 + i, i in [0,16): 48 consecutive floats
        v2f px[8], py[8], pz[8], dist[8];
        {
            float f[48];
            float4* fq = (float4*)f;
            const float4* s4 = (const float4*)bx + t * 12;
#pragma unroll
            for (int q = 0; q < 12; ++q) fq[q] = s4[q];
#pragma unroll
            for (int p = 0; p < 8; ++p) {
                px[p] = (v2f){f[6 * p + 0], f[6 * p + 3]};
                py[p] = (v2f){f[6 * p + 1], f[6 * p + 4]};
                pz[p] = (v2f){f[6 * p + 2], f[6 * p + 5]};
                dist[p] = (v2f){1e38f, 1e38f};
            }
#pragma unroll
            for (int i = 0; i < 16; ++i) {
                const int j  = t * 16 + i;
                const int js = j ^ ((j >> 4) & 7);  // bank swizzle
                pts[js] = make_float4(f[3 * i + 0], f[3 * i + 1], f[3 * i + 2], 0.0f);
            }
        }
        __syncthreads();

        // seed: xyz[b, 0]  (swizzle(0) == 0)
        float4 c0 = pts[0];
        float lx = c0.x, ly = c0.y, lz = c0.z;
        if (t < 3) {
            const float c = (t == 0) ? lx : (t == 1) ? ly : lz;
            const u64 tag = (u64)(u32)(b * NPOINT + 1);   // gw+1, s=0
            __hip_atomic_store(&bslot[t], (tag << 32) | (u64)__float_as_uint(c),
                               __ATOMIC_RELAXED, __HIP_MEMORY_SCOPE_AGENT);
            oxyz[t] = c;
        }

        for (int s = 1; s < NPOINT; ++s) {
            // --- packed update + serial inline argmax over 16 points ---
            const v2f lx2 = (v2f){lx, lx};
            const v2f ly2 = (v2f){ly, ly};
            const v2f lz2 = (v2f){lz, lz};
            float bestv = -1.0f;
            int   bi    = 0;
#pragma unroll
            for (int p = 0; p < 8; ++p) {
                const v2f dx = px[p] - lx2;
                const v2f dy = py[p] - ly2;
                const v2f dz = pz[p] - lz2;
                const v2f d2 = (dx * dx + dy * dy) + dz * dz;   // contract off -> exact
                const float d0 = fminf(dist[p].x, d2.x);
                const float d1 = fminf(dist[p].y, d2.y);
                dist[p] = (v2f){d0, d1};
                if (d0 > bestv) { bestv = d0; bi = 2 * p; }     // strict > keeps lowest i
                if (d1 > bestv) { bestv = d1; bi = 2 * p + 1; }
            }
            const int besti = (t << 4) + bi;

            // --- wave64 max via DPP (no LDS) ---
            float v = bestv;
            v = dpp_max_step<DPP_ROW_SHR(1)>(v);
            v = dpp_max_step<DPP_ROW_SHR(2)>(v);
            v = dpp_max_step<DPP_ROW_SHR(4)>(v);
            v = dpp_max_step<DPP_ROW_SHR(8)>(v);
            v = dpp_max_step<DPP_BCAST15>(v);
            v = dpp_max_step<DPP_BCAST31>(v);
            const float smax = __int_as_float(__builtin_amdgcn_readlane(__float_as_int(v), 63));

            // leader lane (lowest lane holding the max == lowest index) writes partial
            const u64 m   = __ballot(bestv == smax);
            const int par = s & 1;
            if (lane == (int)__builtin_ctzll(m)) {
                partial[par][w] = ((u64)__float_as_uint(smax) << 32)
                                  | (unsigned)(~besti);
            }
            barrier_lds_only();                     // drains LDS only, not vmcnt

            // --- all lanes scan the 8 partials: depth-3 u64 max tree ---
            const u64* P = partial[par];
            const u64 a0 = P[0], a1 = P[1], a2 = P[2], a3 = P[3];
            const u64 a4 = P[4], a5 = P[5], a6 = P[6], a7 = P[7];
            const u64 bp =
                u64max(u64max(u64max(a0, a1), u64max(a2, a3)),
                       u64max(u64max(a4, a5), u64max(a6, a7)));
            const int idx = (int)(~(unsigned)bp);
            const int js  = idx ^ ((idx >> 4) & 7);
            const float4 cw = pts[js];              // uniform -> broadcast b128
            lx = cw.x; ly = cw.y; lz = cw.z;
            // publish center (b,s): lanes 0..2 in parallel (one 3-lane
            // atomic-store + one 3-lane dword store, fire-and-forget)
            if (t < 3) {
                const float c = (t == 0) ? lx : (t == 1) ? ly : lz;
                const u64 tag = (u64)(u32)(b * NPOINT + s + 1);
                __hip_atomic_store(&bslot[3 * s + t],
                                   (tag << 32) | (u64)__float_as_uint(c),
                                   __ATOMIC_RELAXED, __HIP_MEMORY_SCOPE_AGENT);
                oxyz[3 * s + t] = c;
            }
        }
    } else {
        // ================= worker role =================
        for (;;) {
            if (t == 0) jobsh = (int)atomicAdd(counter, 1u);
            __syncthreads();                        // also fences qidx reuse
            const int job = jobsh;
            if (job >= NJOBS) break;                // uniform exit

            const int half = t >> 8;                // 0: center A, 1: center B
            const int gw   = job * 2 + half;        // center id
            const int bb   = gw >> 10;
            const int r    = (t >> 6) & 3;          // quarter within center group

            // --- wait for center coords (3 tagged words, uniform-addr poll) ---
            const u32 tag = (u32)(gw + 1);
            u64* sl = slots + (size_t)gw * 3;
            u64 w0, w1, w2;
            for (;;) {
                w0 = __hip_atomic_load(&sl[0], __ATOMIC_RELAXED, __HIP_MEMORY_SCOPE_AGENT);
                w1 = __hip_atomic_load(&sl[1], __ATOMIC_RELAXED, __HIP_MEMORY_SCOPE_AGENT);
                w2 = __hip_atomic_load(&sl[2], __ATOMIC_RELAXED, __HIP_MEMORY_SCOPE_AGENT);
                if ((u32)(w0 >> 32) == tag && (u32)(w1 >> 32) == tag &&
                    (u32)(w2 >> 32) == tag) break;
                __builtin_amdgcn_s_sleep(32);
            }
            const float cx = __uint_as_float((u32)w0);
            const float cy = __uint_as_float((u32)w1);
            const float cz = __uint_as_float((u32)w2);

            // --- scan this wave's quarter: 2048 pts, 8 superrounds of 256 ---
            const float* bxr = xyz + (size_t)bb * NPTS * 3;
            int k = 0;
            const int qbase = r << 11;
            for (int base = qbase; base < qbase + 2048; base += 256) {
                float qx[4], qy[4], qz[4];
#pragma unroll
                for (int u = 0; u < 4; ++u) {
                    const int j = base + u * 64 + lane;
                    qx[u] = bxr[3 * j + 0];
                    qy[u] = bxr[3 * j + 1];
                    qz[u] = bxr[3 * j + 2];
                }
                bool in[4];
#pragma unroll
                for (int u = 0; u < 4; ++u) {
                    const float dx = qx[u] - cx;
                    const float dy = qy[u] - cy;
                    const float dz = qz[u] - cz;
                    const float d2 = (dx * dx + dy * dy) + dz * dz;   // contract off
                    in[u] = d2 < R2;
                }
#pragma unroll
                for (int u = 0; u < 4; ++u) {
                    const u64 mu = __ballot(in[u]);
                    const int pre = __popcll(mu & ((1ull << lane) - 1ull));
                    if (in[u] && (k + pre) < NSAMPLE) qidx[half][r][k + pre] = base + u * 64 + lane;
                    k += __popcll(mu);
                }
                if (k >= NSAMPLE) break;            // one exit check per superround
            }
            if (k > NSAMPLE) k = NSAMPLE;
            if (lane == 0) qcnt[half][r] = k;
            __syncthreads();

            // --- prefix-merge: first NSAMPLE of the concatenated quarters ---
            const int c0n = qcnt[half][0], c1n = qcnt[half][1];
            const int c2n = qcnt[half][2], c3n = qcnt[half][3];
            const int o1 = c0n, o2 = c0n + c1n, o3 = o2 + c2n;
            const int total = o3 + c3n;
            const int kk = total < NSAMPLE ? total : NSAMPLE;
            const int rq = (c0n > 0) ? 0 : (c1n > 0) ? 1 : (c2n > 0) ? 2 : 3;
            const int firstIdx = qidx[half][rq][0];

            // --- gather: 32x35 output elems across 256 threads, coalesced ---
            float*       o    = out + (size_t)gw * NSAMPLE * OUTC;
            const float* prow = points + (size_t)bb * NPTS * CHANC;
            const int t256 = t & 255;
            for (int e = t256; e < NSAMPLE * OUTC; e += 256) {
                const int sI = e / OUTC;
                const int c  = e - sI * OUTC;
                int j;
                if (sI < kk) {
                    const int rr  = (int)(sI >= o1) + (int)(sI >= o2) + (int)(sI >= o3);
                    const int off = (rr == 0) ? 0 : (rr == 1) ? o1 : (rr == 2) ? o2 : o3;
                    j = qidx[half][rr][sI - off];
                } else {
                    j = firstIdx;
                }
                float v;
                if (c < 3) {
                    const float pv = bxr[3 * j + c];
                    const float cc = (c == 0) ? cx : (c == 1) ? cy : cz;
                    v = pv - cc;
                } else {
                    v = prow[j * CHANC + (c - 3)];
                }
                o[e] = v;   // consecutive lanes -> consecutive addresses (coalesced)
            }
            // loop: next job's top barrier separates qidx reuse
        }
    }
}

// ---------------------------------------------------------------------------
extern "C" void kernel_launch(void* const* d_in, const int* in_sizes, int n_in,
                              void* d_out, int out_size, void* d_ws, size_t ws_size,
                              hipStream_t stream) {
    const float* xyz    = (const float*)d_in[0];   // (8, 8192, 3)  fp32
    const float* points = (const float*)d_in[1];   // (8, 8192, 32) fp32
    float* new_xyz    = (float*)d_out;                         // (8,1024,3)
    float* new_points = new_xyz + (size_t)BATCH * NPOINT * 3;  // (8,1024,32,35)

    u64* slots   = (u64*)d_ws;                                 // 8192 x 3 tagged words
    u32* counter = (u32*)((char*)d_ws + (size_t)BATCH * NPOINT * 3 * sizeof(u64));

    // kill stale tags + job counter from previous graph replay (~192 KB)
    hipMemsetAsync(d_ws, 0, (size_t)BATCH * NPOINT * 3 * sizeof(u64) + 64, stream);

    // plain launch: co-residency by capacity (256 blocks, 1/CU LDS-forced)
    fused_kernel<<<NBLK, NTHR, 0, stream>>>(xyz, points, new_xyz, new_points,
                                            slots, counter);
}